// Round 2
// baseline (442.085 us; speedup 1.0000x reference)
//
#include <hip/hip_runtime.h>
#include <hip/hip_bf16.h>

#define DIMD 256
#define SLEN 4096
#define KT 32

typedef __attribute__((ext_vector_type(8))) short short8;
typedef __attribute__((ext_vector_type(4))) float f32x4;

__device__ __forceinline__ ushort f2bf(float x) {
  union { float f; unsigned u; } v; v.f = x;
  unsigned r = v.u + 0x7fffu + ((v.u >> 16) & 1u);
  return (ushort)(r >> 16);
}

// ---------------- QKV projection: [16384,256] @ [256,768] + b ----------------
// fp32 compute, bf16 outputs. Q pre-scaled by 1/sqrt(256). V stored transposed.
__global__ __launch_bounds__(256) void qkv_proj(const float* __restrict__ X,
                                                const float* __restrict__ W,
                                                const float* __restrict__ bias,
                                                ushort* __restrict__ Qo,
                                                ushort* __restrict__ Ko,
                                                ushort* __restrict__ Vto) {
  __shared__ float Xs[64][33];
  __shared__ float Ws[32][64];
  const int tid = threadIdx.x;
  const int m0 = blockIdx.x * 64;
  const int n0 = blockIdx.y * 64;
  const int tx = tid & 15, ty = tid >> 4;
  float acc[4][4] = {};
  for (int k0 = 0; k0 < 256; k0 += 32) {
    __syncthreads();
    {
      const int r = tid >> 5, c = tid & 31;
#pragma unroll
      for (int it = 0; it < 8; ++it)
        Xs[r + it * 8][c] = X[(size_t)(m0 + r + it * 8) * 256 + k0 + c];
      const int r2 = tid >> 6, c2 = tid & 63;
#pragma unroll
      for (int it = 0; it < 8; ++it)
        Ws[r2 + it * 4][c2] = W[(size_t)(k0 + r2 + it * 4) * 768 + n0 + c2];
    }
    __syncthreads();
#pragma unroll
    for (int k = 0; k < 32; ++k) {
      float a[4], bb[4];
#pragma unroll
      for (int i = 0; i < 4; ++i) a[i] = Xs[ty * 4 + i][k];
#pragma unroll
      for (int j = 0; j < 4; ++j) bb[j] = Ws[k][tx + 16 * j];
#pragma unroll
      for (int i = 0; i < 4; ++i)
#pragma unroll
        for (int j = 0; j < 4; ++j) acc[i][j] += a[i] * bb[j];
    }
  }
#pragma unroll
  for (int j = 0; j < 4; ++j) {
    const int n = n0 + tx + 16 * j;
    const float bv = bias[n];
    const float sc = (n < 256) ? 0.0625f : 1.0f;   // fold 1/sqrt(D) into Q
#pragma unroll
    for (int i = 0; i < 4; ++i) {
      const int m = m0 + ty * 4 + i;
      const ushort h = f2bf((acc[i][j] + bv) * sc);
      if (n < 256)      Qo[(size_t)m * 256 + n] = h;
      else if (n < 512) Ko[(size_t)m * 256 + (n - 256)] = h;
      else {
        const int d = n - 512, bidx = m >> 12, s = m & 4095;
        Vto[((size_t)bidx * 256 + d) * 4096 + s] = h;
      }
    }
  }
}

// ------------- flash attention, KV-split, in-register softmax -------------
// grid = 256*nsplit blocks, 4 waves each; wave owns 16 q-rows over kvn kv-rows.
__global__ __launch_bounds__(256, 3) void flash_attn(const ushort* __restrict__ Q,
                                                     const ushort* __restrict__ K,
                                                     const ushort* __restrict__ Vt,
                                                     float* __restrict__ Out,
                                                     float* __restrict__ Op,
                                                     float* __restrict__ MLp,
                                                     int nsplit, int kvn) {
  __shared__ __attribute__((aligned(16))) ushort Ks[KT * DIMD];   // swizzled
  __shared__ __attribute__((aligned(16))) ushort Vs[DIMD * KT];   // swizzled
  __shared__ __attribute__((aligned(16))) ushort Ps[4][16][40];

  const int tid = threadIdx.x;
  const int w = tid >> 6, lane = tid & 63;
  // XCD-aware bijective swizzle (gridDim multiple of 8)
  const int nwg = gridDim.x;
  const int wg = (blockIdx.x & 7) * (nwg >> 3) + (blockIdx.x >> 3);
  const int split = wg >> 8;
  const int rest = wg & 255;
  const int b = rest >> 6;
  const int q0 = (rest & 63) * 64;
  const int qa = lane & 15, hi = lane >> 4;

  // Q fragments hoisted (Q already scaled by 1/16)
  const ushort* Qrow = Q + (size_t)(b * SLEN + q0 + w * 16 + qa) * DIMD;
  short8 qf[8];
#pragma unroll
  for (int dc = 0; dc < 8; ++dc)
    qf[dc] = *(const short8*)(Qrow + dc * 32 + hi * 8);

  f32x4 zero = {0.f, 0.f, 0.f, 0.f};
  f32x4 acc[16];
#pragma unroll
  for (int dc = 0; dc < 16; ++dc) acc[dc] = zero;
  float mold[4], lrun[4];
#pragma unroll
  for (int r = 0; r < 4; ++r) { mold[r] = -1e30f; lrun[r] = 0.f; }

  const ushort* Kb  = K  + (size_t)b * SLEN * DIMD;
  const ushort* Vtb = Vt + (size_t)b * DIMD * SLEN;
  const int kv_begin = split * kvn, kv_end = kv_begin + kvn;

  // staging decomposition (coalesced global reads)
  const int kr = tid >> 3, kc = (tid & 7) * 16;      // K: row 0..31, byte-col
  const int vd = tid >> 2, vc = (tid & 3) * 16;      // V: d-row 0..63, byte-col

  for (int kv0 = kv_begin; kv0 < kv_end; kv0 += KT) {
    // ---- stage K [32][256] and Vt [256][32] with XOR swizzle
#pragma unroll
    for (int it = 0; it < 4; ++it) {
      const int cb = kc + it * 128;
      short8 v = *(const short8*)(Kb + (size_t)(kv0 + kr) * DIMD + (cb >> 1));
      *(short8*)((char*)Ks + ((kr * 512 + cb) ^ ((kr & 7) << 4))) = v;
    }
#pragma unroll
    for (int it = 0; it < 4; ++it) {
      const int d = vd + it * 64;
      short8 v = *(const short8*)(Vtb + (size_t)d * SLEN + kv0 + (vc >> 1));
      *(short8*)((char*)Vs + ((d * 64 + vc) ^ ((d & 3) << 4))) = v;
    }
    __syncthreads();

    // ---- S = Q K^T (pre-scaled): rows hi*4+r, cols qa / qa+16
    f32x4 s0 = zero, s1 = zero;
#pragma unroll
    for (int dc = 0; dc < 8; ++dc) {
      const int cb = dc * 64 + hi * 16;
      short8 kf0 = *(const short8*)((const char*)Ks + ((qa * 512 + cb) ^ ((qa & 7) << 4)));
      short8 kf1 = *(const short8*)((const char*)Ks + (((qa + 16) * 512 + cb) ^ ((qa & 7) << 4)));
      s0 = __builtin_amdgcn_mfma_f32_16x16x32_bf16(qf[dc], kf0, s0, 0, 0, 0);
      s1 = __builtin_amdgcn_mfma_f32_16x16x32_bf16(qf[dc], kf1, s1, 0, 0, 0);
    }

    // ---- in-register online softmax (reduce across 16 qa-lanes)
    float p0[4], p1[4], fr[4];
#pragma unroll
    for (int r = 0; r < 4; ++r) {
      float m2 = fmaxf(s0[r], s1[r]);
      m2 = fmaxf(m2, __shfl_xor(m2, 1));
      m2 = fmaxf(m2, __shfl_xor(m2, 2));
      m2 = fmaxf(m2, __shfl_xor(m2, 4));
      m2 = fmaxf(m2, __shfl_xor(m2, 8));
      const float mnew = fmaxf(mold[r], m2);
      fr[r] = __expf(mold[r] - mnew);
      p0[r] = __expf(s0[r] - mnew);
      p1[r] = __expf(s1[r] - mnew);
      mold[r] = mnew;
      float ls = p0[r] + p1[r];
      ls += __shfl_xor(ls, 1);
      ls += __shfl_xor(ls, 2);
      ls += __shfl_xor(ls, 4);
      ls += __shfl_xor(ls, 8);
      lrun[r] = lrun[r] * fr[r] + ls;
    }
#pragma unroll
    for (int dc = 0; dc < 16; ++dc)
#pragma unroll
      for (int r = 0; r < 4; ++r) acc[dc][r] *= fr[r];

    // ---- P -> bf16 -> LDS (per-wave), then PV
#pragma unroll
    for (int r = 0; r < 4; ++r) {
      Ps[w][hi * 4 + r][qa]      = f2bf(p0[r]);
      Ps[w][hi * 4 + r][qa + 16] = f2bf(p1[r]);
    }
    short8 pf = *(const short8*)&Ps[w][qa][hi * 8];
#pragma unroll
    for (int dc = 0; dc < 16; ++dc) {
      const int d = dc * 16 + qa;
      short8 vf = *(const short8*)((const char*)Vs + ((d * 64 + hi * 16) ^ ((d & 3) << 4)));
      acc[dc] = __builtin_amdgcn_mfma_f32_16x16x32_bf16(pf, vf, acc[dc], 0, 0, 0);
    }
    __syncthreads();
  }

  // ---- epilogue
  if (nsplit == 1) {
    float inv[4];
#pragma unroll
    for (int r = 0; r < 4; ++r) inv[r] = 1.f / lrun[r];
    float* Ob = Out + (size_t)(b * SLEN + q0 + w * 16) * DIMD;
#pragma unroll
    for (int dc = 0; dc < 16; ++dc)
#pragma unroll
      for (int r = 0; r < 4; ++r)
        Ob[(size_t)(hi * 4 + r) * DIMD + dc * 16 + qa] = acc[dc][r] * inv[r];
  } else {
    const size_t qrow0 = (size_t)b * SLEN + q0 + w * 16;
#pragma unroll
    for (int dc = 0; dc < 16; ++dc)
#pragma unroll
      for (int r = 0; r < 4; ++r)
        Op[((qrow0 + hi * 4 + r) * nsplit + split) * DIMD + dc * 16 + qa] = acc[dc][r];
    if (qa == 0) {
#pragma unroll
      for (int r = 0; r < 4; ++r) {
        const size_t i = (qrow0 + hi * 4 + r) * nsplit + split;
        MLp[i * 2] = mold[r];
        MLp[i * 2 + 1] = lrun[r];
      }
    }
  }
}

// ------------- merge partials across kv-splits -------------
__global__ __launch_bounds__(256) void attn_merge(const float* __restrict__ Op,
                                                  const float* __restrict__ MLp,
                                                  float* __restrict__ Out, int nsplit) {
  const int q = blockIdx.x, d = threadIdx.x;
  float M = -1e30f;
  for (int i = 0; i < nsplit; ++i) M = fmaxf(M, MLp[((size_t)q * nsplit + i) * 2]);
  float L = 0.f, o = 0.f;
  for (int i = 0; i < nsplit; ++i) {
    const float wgt = __expf(MLp[((size_t)q * nsplit + i) * 2] - M);
    L += wgt * MLp[((size_t)q * nsplit + i) * 2 + 1];
    o += wgt * Op[((size_t)q * nsplit + i) * DIMD + d];
  }
  Out[(size_t)q * DIMD + d] = o / L;
}

extern "C" void kernel_launch(void* const* d_in, const int* in_sizes, int n_in,
                              void* d_out, int out_size, void* d_ws, size_t ws_size,
                              hipStream_t stream) {
  const float* X    = (const float*)d_in[0];
  const float* W    = (const float*)d_in[1];
  const float* bias = (const float*)d_in[2];
  char* wsb = (char*)d_ws;
  ushort* qw  = (ushort*)wsb;
  ushort* kw  = qw + (size_t)16384 * 256;
  ushort* vtw = kw + (size_t)16384 * 256;
  const size_t qkv_bytes = (size_t)3 * 16384 * 256 * 2;   // 24 MiB
  const size_t per_split = (size_t)16384 * 256 * 4 + (size_t)16384 * 8;
  int nsplit = 1;
  if (ws_size >= qkv_bytes + 4 * per_split)      nsplit = 4;
  else if (ws_size >= qkv_bytes + 2 * per_split) nsplit = 2;
  float* Op  = (float*)(wsb + qkv_bytes);
  float* MLp = Op + (size_t)16384 * nsplit * 256;

  qkv_proj<<<dim3(256, 12), 256, 0, stream>>>(X, W, bias, qw, kw, vtw);
  flash_attn<<<dim3(256 * nsplit), 256, 0, stream>>>(qw, kw, vtw, (float*)d_out,
                                                     Op, MLp, nsplit, 4096 / nsplit);
  if (nsplit > 1)
    attn_merge<<<dim3(16384), 256, 0, stream>>>(Op, MLp, (float*)d_out, nsplit);
}

// Round 4
// 341.884 us; speedup vs baseline: 1.2931x; 1.2931x over previous
//
#include <hip/hip_runtime.h>
#include <hip/hip_bf16.h>

#define DIMD 256
#define SLEN 4096
#define KT 32

typedef __attribute__((ext_vector_type(8))) short short8;
typedef __attribute__((ext_vector_type(4))) short bf16x4;
typedef __attribute__((ext_vector_type(4))) float f32x4;

__device__ __forceinline__ ushort f2bf(float x) {
  union { float f; unsigned u; } v; v.f = x;
  unsigned r = v.u + 0x7fffu + ((v.u >> 16) & 1u);
  return (ushort)(r >> 16);
}

// ---------------- QKV projection: [16384,256] @ [256,768] + b ----------------
// fp32 compute, bf16 outputs. Q pre-scaled by 1/sqrt(256). V stored transposed.
__global__ __launch_bounds__(256) void qkv_proj(const float* __restrict__ X,
                                                const float* __restrict__ W,
                                                const float* __restrict__ bias,
                                                ushort* __restrict__ Qo,
                                                ushort* __restrict__ Ko,
                                                ushort* __restrict__ Vto) {
  __shared__ float Xs[64][33];
  __shared__ float Ws[32][64];
  const int tid = threadIdx.x;
  const int m0 = blockIdx.x * 64;
  const int n0 = blockIdx.y * 64;
  const int tx = tid & 15, ty = tid >> 4;
  float acc[4][4] = {};
  for (int k0 = 0; k0 < 256; k0 += 32) {
    __syncthreads();
    {
      const int r = tid >> 5, c = tid & 31;
#pragma unroll
      for (int it = 0; it < 8; ++it)
        Xs[r + it * 8][c] = X[(size_t)(m0 + r + it * 8) * 256 + k0 + c];
      const int r2 = tid >> 6, c2 = tid & 63;
#pragma unroll
      for (int it = 0; it < 8; ++it)
        Ws[r2 + it * 4][c2] = W[(size_t)(k0 + r2 + it * 4) * 768 + n0 + c2];
    }
    __syncthreads();
#pragma unroll
    for (int k = 0; k < 32; ++k) {
      float a[4], bb[4];
#pragma unroll
      for (int i = 0; i < 4; ++i) a[i] = Xs[ty * 4 + i][k];
#pragma unroll
      for (int j = 0; j < 4; ++j) bb[j] = Ws[k][tx + 16 * j];
#pragma unroll
      for (int i = 0; i < 4; ++i)
#pragma unroll
        for (int j = 0; j < 4; ++j) acc[i][j] += a[i] * bb[j];
    }
  }
#pragma unroll
  for (int j = 0; j < 4; ++j) {
    const int n = n0 + tx + 16 * j;
    const float bv = bias[n];
    const float sc = (n < 256) ? 0.0625f : 1.0f;   // fold 1/sqrt(D) into Q
#pragma unroll
    for (int i = 0; i < 4; ++i) {
      const int m = m0 + ty * 4 + i;
      const ushort h = f2bf((acc[i][j] + bv) * sc);
      if (n < 256)      Qo[(size_t)m * 256 + n] = h;
      else if (n < 512) Ko[(size_t)m * 256 + (n - 256)] = h;
      else {
        const int d = n - 512, bidx = m >> 12, s = m & 4095;
        Vto[((size_t)bidx * 256 + d) * 4096 + s] = h;
      }
    }
  }
}

// ------- flash attention: swapped QK^T, in-register softmax + P, KV-split -------
__global__ __launch_bounds__(256, 4) void flash_attn(const ushort* __restrict__ Q,
                                                     const ushort* __restrict__ K,
                                                     const ushort* __restrict__ Vt,
                                                     float* __restrict__ Out,
                                                     float* __restrict__ Op,
                                                     float* __restrict__ MLp,
                                                     int nsplit, int kvn) {
  __shared__ __attribute__((aligned(16))) ushort Ks[KT * DIMD];   // swizzled
  __shared__ __attribute__((aligned(16))) ushort Vs[DIMD * KT];   // swizzled

  const int tid = threadIdx.x;
  const int w = tid >> 6, lane = tid & 63;
  const int nwg = gridDim.x;
  const int wg = (blockIdx.x & 7) * (nwg >> 3) + (blockIdx.x >> 3);
  const int split = wg >> 8;
  const int rest = wg & 255;
  const int b = rest >> 6;
  const int q0 = (rest & 63) * 64;
  const int qa = lane & 15, hi = lane >> 4;

  // Q fragments hoisted (Q already scaled by 1/16)
  const ushort* Qrow = Q + (size_t)(b * SLEN + q0 + w * 16 + qa) * DIMD;
  short8 qf[8];
#pragma unroll
  for (int dc = 0; dc < 8; ++dc)
    qf[dc] = *(const short8*)(Qrow + dc * 32 + hi * 8);

  f32x4 zero = {0.f, 0.f, 0.f, 0.f};
  f32x4 acc[16];
#pragma unroll
  for (int dc = 0; dc < 16; ++dc) acc[dc] = zero;
  float mold = -1e30f, lrun = 0.f;   // per-lane scalars, q = qa

  const ushort* Kb  = K  + (size_t)b * SLEN * DIMD;
  const ushort* Vtb = Vt + (size_t)b * DIMD * SLEN;
  const int kv_begin = split * kvn, kv_end = kv_begin + kvn;

  const int kr = tid >> 3, kc = (tid & 7) * 16;      // K staging
  const int vd = tid >> 2, vc = (tid & 3) * 16;      // V staging

  for (int kv0 = kv_begin; kv0 < kv_end; kv0 += KT) {
    // ---- stage K [32][256] and Vt [256][32] with XOR swizzle
#pragma unroll
    for (int it = 0; it < 4; ++it) {
      const int cb = kc + it * 128;
      short8 v = *(const short8*)(Kb + (size_t)(kv0 + kr) * DIMD + (cb >> 1));
      *(short8*)((char*)Ks + ((kr * 512 + cb) ^ ((kr & 7) << 4))) = v;
    }
#pragma unroll
    for (int it = 0; it < 4; ++it) {
      const int d = vd + it * 64;
      short8 v = *(const short8*)(Vtb + (size_t)d * SLEN + kv0 + (vc >> 1));
      *(short8*)((char*)Vs + ((d * 64 + vc) ^ ((d & 3) << 4))) = v;
    }
    __syncthreads();

    // ---- S^T = K Q^T (Q pre-scaled): lane (qa,hi) holds S[k=hi*4+r(+16)][q=qa]
    f32x4 s0 = zero, s1 = zero;
#pragma unroll
    for (int dc = 0; dc < 8; ++dc) {
      const int cb = dc * 64 + hi * 16;
      short8 kf0 = *(const short8*)((const char*)Ks + ((qa * 512 + cb) ^ ((qa & 7) << 4)));
      short8 kf1 = *(const short8*)((const char*)Ks + (((qa + 16) * 512 + cb) ^ ((qa & 7) << 4)));
      s0 = __builtin_amdgcn_mfma_f32_16x16x32_bf16(kf0, qf[dc], s0, 0, 0, 0);
      s1 = __builtin_amdgcn_mfma_f32_16x16x32_bf16(kf1, qf[dc], s1, 0, 0, 0);
    }

    // ---- in-register online softmax for row q=qa (8 in-lane + 2 shfl levels)
    float m8 = fmaxf(fmaxf(fmaxf(s0[0], s0[1]), fmaxf(s0[2], s0[3])),
                     fmaxf(fmaxf(s1[0], s1[1]), fmaxf(s1[2], s1[3])));
    m8 = fmaxf(m8, __shfl_xor(m8, 16));
    m8 = fmaxf(m8, __shfl_xor(m8, 32));
    if (!__all(m8 - mold <= 4.0f)) {      // defer-max (THR=4)
      const float mnew = fmaxf(mold, m8);
      const float fr = __expf(mold - mnew);
      mold = mnew;
      lrun *= fr;
      float frr[4];
#pragma unroll
      for (int r = 0; r < 4; ++r) frr[r] = __shfl(fr, hi * 4 + r);
#pragma unroll
      for (int dc = 0; dc < 16; ++dc)
#pragma unroll
        for (int r = 0; r < 4; ++r) acc[dc][r] *= frr[r];
    }
    float p0[4], p1[4], ls = 0.f;
#pragma unroll
    for (int r = 0; r < 4; ++r) {
      p0[r] = __expf(s0[r] - mold);
      p1[r] = __expf(s1[r] - mold);
      ls += p0[r] + p1[r];
    }
    ls += __shfl_xor(ls, 16);
    ls += __shfl_xor(ls, 32);
    lrun += ls;

    // ---- PV entirely from registers: A = P (own k-perm), B = V loaded to match
    short8 af;
#pragma unroll
    for (int r = 0; r < 4; ++r) {
      af[r]     = (short)f2bf(p0[r]);   // k = hi*4+r      at pos j=r
      af[4 + r] = (short)f2bf(p1[r]);   // k = 16+hi*4+r   at pos j=4+r
    }
#pragma unroll
    for (int dc = 0; dc < 16; ++dc) {
      const int d = dc * 16 + qa;
      const char* vrow = (const char*)Vs + d * 64;
      const int sw = (d & 3) << 4;
      bf16x4 v0 = *(const bf16x4*)(vrow + ((hi * 8) ^ sw));        // k=hi*4+0..3
      bf16x4 v1 = *(const bf16x4*)(vrow + ((32 + hi * 8) ^ sw));   // k=16+hi*4+0..3
      short8 vf = {v0[0], v0[1], v0[2], v0[3], v1[0], v1[1], v1[2], v1[3]};
      acc[dc] = __builtin_amdgcn_mfma_f32_16x16x32_bf16(af, vf, acc[dc], 0, 0, 0);
    }
    __syncthreads();
  }

  // ---- epilogue: acc[dc][r] = O[q=hi*4+r][d=dc*16+qa] (unnormalized)
  if (nsplit == 1) {
    float inv[4];
#pragma unroll
    for (int r = 0; r < 4; ++r) inv[r] = 1.f / __shfl(lrun, hi * 4 + r);
    float* Ob = Out + (size_t)(b * SLEN + q0 + w * 16) * DIMD;
#pragma unroll
    for (int dc = 0; dc < 16; ++dc)
#pragma unroll
      for (int r = 0; r < 4; ++r)
        Ob[(size_t)(hi * 4 + r) * DIMD + dc * 16 + qa] = acc[dc][r] * inv[r];
  } else {
    const size_t qrow0 = (size_t)b * SLEN + q0 + w * 16;
#pragma unroll
    for (int dc = 0; dc < 16; ++dc)
#pragma unroll
      for (int r = 0; r < 4; ++r)
        Op[((qrow0 + hi * 4 + r) * nsplit + split) * DIMD + dc * 16 + qa] = acc[dc][r];
    if (hi == 0) {   // lane qa owns q=qa's m,l
      const size_t i = (qrow0 + qa) * nsplit + split;
      MLp[i * 2] = mold;
      MLp[i * 2 + 1] = lrun;
    }
  }
}

// ------------- merge partials across kv-splits -------------
__global__ __launch_bounds__(256) void attn_merge(const float* __restrict__ Op,
                                                  const float* __restrict__ MLp,
                                                  float* __restrict__ Out, int nsplit) {
  const int q = blockIdx.x, d = threadIdx.x;
  float M = -1e30f;
  for (int i = 0; i < nsplit; ++i) M = fmaxf(M, MLp[((size_t)q * nsplit + i) * 2]);
  float L = 0.f, o = 0.f;
  for (int i = 0; i < nsplit; ++i) {
    const float wgt = __expf(MLp[((size_t)q * nsplit + i) * 2] - M);
    L += wgt * MLp[((size_t)q * nsplit + i) * 2 + 1];
    o += wgt * Op[((size_t)q * nsplit + i) * DIMD + d];
  }
  Out[(size_t)q * DIMD + d] = o / L;
}

extern "C" void kernel_launch(void* const* d_in, const int* in_sizes, int n_in,
                              void* d_out, int out_size, void* d_ws, size_t ws_size,
                              hipStream_t stream) {
  const float* X    = (const float*)d_in[0];
  const float* W    = (const float*)d_in[1];
  const float* bias = (const float*)d_in[2];
  char* wsb = (char*)d_ws;
  ushort* qw  = (ushort*)wsb;
  ushort* kw  = qw + (size_t)16384 * 256;
  ushort* vtw = kw + (size_t)16384 * 256;
  const size_t qkv_bytes = (size_t)3 * 16384 * 256 * 2;   // 24 MiB
  const size_t per_split = (size_t)16384 * 256 * 4 + (size_t)16384 * 8;
  int nsplit = 1;
  if (ws_size >= qkv_bytes + 4 * per_split)      nsplit = 4;
  else if (ws_size >= qkv_bytes + 2 * per_split) nsplit = 2;
  float* Op  = (float*)(wsb + qkv_bytes);
  float* MLp = Op + (size_t)16384 * nsplit * 256;

  qkv_proj<<<dim3(256, 12), 256, 0, stream>>>(X, W, bias, qw, kw, vtw);
  flash_attn<<<dim3(256 * nsplit), 256, 0, stream>>>(qw, kw, vtw, (float*)d_out,
                                                     Op, MLp, nsplit, 4096 / nsplit);
  if (nsplit > 1)
    attn_merge<<<dim3(16384), 256, 0, stream>>>(Op, MLp, (float*)d_out, nsplit);
}

// Round 5
// 165.410 us; speedup vs baseline: 2.6727x; 2.0669x over previous
//
#include <hip/hip_runtime.h>
#include <hip/hip_bf16.h>

#define DIMD 256
#define SLEN 4096
#define KT 32

typedef __attribute__((ext_vector_type(8))) short short8;
typedef __attribute__((ext_vector_type(4))) short bf16x4;
typedef __attribute__((ext_vector_type(4))) float f32x4;
typedef unsigned int u32;

__device__ __forceinline__ ushort f2bf(float x) {
  union { float f; unsigned u; } v; v.f = x;
  unsigned r = v.u + 0x7fffu + ((v.u >> 16) & 1u);
  return (ushort)(r >> 16);
}

// async 16B global->LDS DMA; lds base must be wave-uniform, lanes fill base+lane*16
typedef __attribute__((address_space(1))) const u32 g_u32;
typedef __attribute__((address_space(3))) u32 l_u32;
__device__ __forceinline__ void gld_lds16(const void* g, void* l) {
  __builtin_amdgcn_global_load_lds((g_u32*)g, (l_u32*)l, 16, 0, 0);
}

// ---------------- W transpose + bf16: Wt[n][k] from W[k][n] ----------------
__global__ __launch_bounds__(256) void wt_prep(const float* __restrict__ W,
                                               ushort* __restrict__ Wt) {
  __shared__ float T[32][257];
  const int t = threadIdx.x;
  const int n0 = blockIdx.x * 32;
#pragma unroll
  for (int pass = 0; pass < 8; ++pass) {
    const int k = pass * 32 + (t >> 3);
    const int c4 = (t & 7) * 4;
    const float4 f = *(const float4*)&W[(size_t)k * 768 + n0 + c4];
    T[c4 + 0][k] = f.x; T[c4 + 1][k] = f.y; T[c4 + 2][k] = f.z; T[c4 + 3][k] = f.w;
  }
  __syncthreads();
  const int n = t >> 3, kb = (t & 7) * 32;
#pragma unroll
  for (int j8 = 0; j8 < 4; ++j8) {
    short8 o;
#pragma unroll
    for (int j = 0; j < 8; ++j) o[j] = (short)f2bf(T[n][kb + j8 * 8 + j]);
    *(short8*)&Wt[(size_t)(n0 + n) * 256 + kb + j8 * 8] = o;
  }
}

// ---------------- MFMA QKV projection: [16384,256] @ [256,768] + b ----------------
// blockIdx.y selects segment (0=Q scaled 1/16, 1=K, 2=V transposed+j-permuted).
__global__ __launch_bounds__(256, 2) void qkv_proj(const float* __restrict__ X,
                                                   const ushort* __restrict__ Wt,
                                                   const float* __restrict__ bias,
                                                   ushort* __restrict__ Qo,
                                                   ushort* __restrict__ Ko,
                                                   ushort* __restrict__ Vto) {
  __shared__ ushort Xs[128 * 36];   // 72B-padded rows -> conflict-free b128 frags
  __shared__ ushort Ws[256 * 36];
  const int tid = threadIdx.x;
  const int w = tid >> 6, lane = tid & 63;
  const int qa = lane & 15, hi = lane >> 4;
  const int m0 = blockIdx.x * 128;
  const int seg = blockIdx.y;
  const int n0 = seg * 256;

  f32x4 acc[2][16];
#pragma unroll
  for (int t = 0; t < 2; ++t)
#pragma unroll
    for (int dc = 0; dc < 16; ++dc) acc[t][dc] = (f32x4){0.f, 0.f, 0.f, 0.f};

  for (int k0 = 0; k0 < 256; k0 += 32) {
    __syncthreads();
#pragma unroll
    for (int pass = 0; pass < 4; ++pass) {   // X tile [128][32] fp32 -> bf16
      const int row = pass * 32 + (tid >> 3);
      const int c = tid & 7;
      const float4 f = *(const float4*)&X[(size_t)(m0 + row) * 256 + k0 + c * 4];
      bf16x4 h = {(short)f2bf(f.x), (short)f2bf(f.y), (short)f2bf(f.z), (short)f2bf(f.w)};
      *(bf16x4*)&Xs[row * 36 + c * 4] = h;
    }
#pragma unroll
    for (int pass = 0; pass < 4; ++pass) {   // Wt tile [256][32] bf16
      const int n = pass * 64 + (tid >> 2);
      const int c = (tid & 3) * 8;
      short8 v = *(const short8*)&Wt[(size_t)(n0 + n) * 256 + k0 + c];
      *(short8*)&Ws[n * 36 + c] = v;
    }
    __syncthreads();
    const short8 xf0 = *(const short8*)&Xs[(w * 32 + qa) * 36 + hi * 8];
    const short8 xf1 = *(const short8*)&Xs[(w * 32 + 16 + qa) * 36 + hi * 8];
    __builtin_amdgcn_s_setprio(1);
#pragma unroll
    for (int dc = 0; dc < 16; ++dc) {
      const short8 wf = *(const short8*)&Ws[(dc * 16 + qa) * 36 + hi * 8];
      acc[0][dc] = __builtin_amdgcn_mfma_f32_16x16x32_bf16(xf0, wf, acc[0][dc], 0, 0, 0);
      acc[1][dc] = __builtin_amdgcn_mfma_f32_16x16x32_bf16(xf1, wf, acc[1][dc], 0, 0, 0);
    }
    __builtin_amdgcn_s_setprio(0);
  }

  const float sc = (seg == 0) ? 0.0625f : 1.0f;
#pragma unroll
  for (int dc = 0; dc < 16; ++dc) {
    const int nn = dc * 16 + qa;
    const float bv = bias[n0 + nn];
#pragma unroll
    for (int t = 0; t < 2; ++t) {
#pragma unroll
      for (int r = 0; r < 4; ++r) {
        const int m = m0 + w * 32 + t * 16 + hi * 4 + r;
        const ushort h = f2bf((acc[t][dc][r] + bv) * sc);
        if (seg == 0)      Qo[(size_t)m * 256 + nn] = h;
        else if (seg == 1) Ko[(size_t)m * 256 + nn] = h;
        else {
          const int bi = m >> 12, s = m & 4095;
          const int sp = (s & ~31) | ((s & 3) | (((s >> 4) & 1) << 2) | (((s >> 2) & 3) << 3));
          Vto[((size_t)bi * 256 + nn) * 4096 + sp] = h;
        }
      }
    }
  }
}

// ---- stage one K[32][256] + Vt[256][32] tile via DMA, source pre-swizzled ----
__device__ __forceinline__ void stage_kv(ushort* KsB, ushort* VsB,
                                         const ushort* Kb, const ushort* Vtb,
                                         int kv0, int w, int lane) {
#pragma unroll
  for (int it = 0; it < 4; ++it) {
    const int row = w * 8 + it * 2 + (lane >> 5);
    const int cb = (lane & 31) * 16;
    const char* src = (const char*)Kb + (size_t)(kv0 + row) * 512 + (cb ^ ((row & 7) << 4));
    gld_lds16(src, (char*)KsB + w * 4096 + it * 1024);
  }
#pragma unroll
  for (int it = 0; it < 4; ++it) {
    const int d = w * 64 + it * 16 + (lane >> 2);
    const int cb = (lane & 3) * 16;
    const char* src = (const char*)Vtb + (size_t)d * 8192 + (size_t)kv0 * 2 + (cb ^ ((d & 3) << 4));
    gld_lds16(src, (char*)VsB + w * 4096 + it * 1024);
  }
}

// ------- flash attention: 4 waves x 32 q-rows, dbuf DMA staging, reg softmax -------
__global__ __launch_bounds__(256, 2) void flash_attn(const ushort* __restrict__ Q,
                                                     const ushort* __restrict__ K,
                                                     const ushort* __restrict__ Vt,
                                                     float* __restrict__ Out,
                                                     float* __restrict__ Op,
                                                     float* __restrict__ MLp,
                                                     int nsplit, int kvn) {
  __shared__ __attribute__((aligned(16))) ushort Ks[2][KT * DIMD];
  __shared__ __attribute__((aligned(16))) ushort Vs[2][DIMD * KT];

  const int tid = threadIdx.x;
  const int w = tid >> 6, lane = tid & 63;
  const int nwg = gridDim.x;                       // 128*nsplit, multiple of 8
  const int wg = (blockIdx.x & 7) * (nwg >> 3) + (blockIdx.x >> 3);
  const int split = wg >> 7;
  const int rest = wg & 127;
  const int b = rest >> 5;
  const int q0 = (rest & 31) * 128;
  const int qa = lane & 15, hi = lane >> 4;

  const ushort* Qr0 = Q + (size_t)(b * SLEN + q0 + w * 32 + qa) * DIMD;
  short8 qf0[8], qf1[8];
#pragma unroll
  for (int dc = 0; dc < 8; ++dc) {
    qf0[dc] = *(const short8*)(Qr0 + dc * 32 + hi * 8);
    qf1[dc] = *(const short8*)(Qr0 + 16 * DIMD + dc * 32 + hi * 8);
  }

  const f32x4 zero = {0.f, 0.f, 0.f, 0.f};
  f32x4 acc[2][16];
#pragma unroll
  for (int t = 0; t < 2; ++t)
#pragma unroll
    for (int dc = 0; dc < 16; ++dc) acc[t][dc] = zero;
  float mold0 = -1e30f, lrun0 = 0.f, mold1 = -1e30f, lrun1 = 0.f;  // q = qa per tile

  const ushort* Kb = K + (size_t)b * SLEN * DIMD;
  const ushort* Vtb = Vt + (size_t)b * DIMD * SLEN;
  const int kv_begin = split * kvn, kv_end = kv_begin + kvn;

  stage_kv(Ks[0], Vs[0], Kb, Vtb, kv_begin, w, lane);
  __syncthreads();
  int buf = 0;

  for (int kv0 = kv_begin; kv0 < kv_end; kv0 += KT) {
    if (kv0 + KT < kv_end)
      stage_kv(Ks[buf ^ 1], Vs[buf ^ 1], Kb, Vtb, kv0 + KT, w, lane);
    const char* KsB = (const char*)Ks[buf];
    const char* VsB = (const char*)Vs[buf];

    // ---- S^T = K Q^T : lane (qa,hi) holds S[k=hi*4+r(+16)][q=qa] per tile
    f32x4 sa0 = zero, sa1 = zero, sb0 = zero, sb1 = zero;
    __builtin_amdgcn_s_setprio(1);
#pragma unroll
    for (int dc = 0; dc < 8; ++dc) {
      const int cb = dc * 64 + hi * 16;
      const short8 kf0 = *(const short8*)(KsB + ((qa * 512 + cb) ^ ((qa & 7) << 4)));
      const short8 kf1 = *(const short8*)(KsB + (((qa + 16) * 512 + cb) ^ ((qa & 7) << 4)));
      sa0 = __builtin_amdgcn_mfma_f32_16x16x32_bf16(kf0, qf0[dc], sa0, 0, 0, 0);
      sa1 = __builtin_amdgcn_mfma_f32_16x16x32_bf16(kf1, qf0[dc], sa1, 0, 0, 0);
      sb0 = __builtin_amdgcn_mfma_f32_16x16x32_bf16(kf0, qf1[dc], sb0, 0, 0, 0);
      sb1 = __builtin_amdgcn_mfma_f32_16x16x32_bf16(kf1, qf1[dc], sb1, 0, 0, 0);
    }
    __builtin_amdgcn_s_setprio(0);

    // ---- in-register online softmax (per tile): 8 in-lane fmax + 2 shfl
    float m8a = fmaxf(fmaxf(fmaxf(sa0[0], sa0[1]), fmaxf(sa0[2], sa0[3])),
                      fmaxf(fmaxf(sa1[0], sa1[1]), fmaxf(sa1[2], sa1[3])));
    float m8b = fmaxf(fmaxf(fmaxf(sb0[0], sb0[1]), fmaxf(sb0[2], sb0[3])),
                      fmaxf(fmaxf(sb1[0], sb1[1]), fmaxf(sb1[2], sb1[3])));
    m8a = fmaxf(m8a, __shfl_xor(m8a, 16)); m8a = fmaxf(m8a, __shfl_xor(m8a, 32));
    m8b = fmaxf(m8b, __shfl_xor(m8b, 16)); m8b = fmaxf(m8b, __shfl_xor(m8b, 32));
    if (!__all(fmaxf(m8a - mold0, m8b - mold1) <= 4.0f)) {   // defer-max THR=4
      const float mn0 = fmaxf(mold0, m8a), fr0 = __expf(mold0 - mn0);
      const float mn1 = fmaxf(mold1, m8b), fr1 = __expf(mold1 - mn1);
      mold0 = mn0; lrun0 *= fr0; mold1 = mn1; lrun1 *= fr1;
      float fA[4], fB[4];
#pragma unroll
      for (int r = 0; r < 4; ++r) { fA[r] = __shfl(fr0, hi * 4 + r); fB[r] = __shfl(fr1, hi * 4 + r); }
#pragma unroll
      for (int dc = 0; dc < 16; ++dc)
#pragma unroll
        for (int r = 0; r < 4; ++r) { acc[0][dc][r] *= fA[r]; acc[1][dc][r] *= fB[r]; }
    }
    short8 af0, af1;
    float ls0 = 0.f, ls1 = 0.f;
#pragma unroll
    for (int r = 0; r < 4; ++r) {
      float p = __expf(sa0[r] - mold0); ls0 += p; af0[r] = (short)f2bf(p);
      p = __expf(sa1[r] - mold0); ls0 += p; af0[4 + r] = (short)f2bf(p);
      p = __expf(sb0[r] - mold1); ls1 += p; af1[r] = (short)f2bf(p);
      p = __expf(sb1[r] - mold1); ls1 += p; af1[4 + r] = (short)f2bf(p);
    }
    ls0 += __shfl_xor(ls0, 16); ls0 += __shfl_xor(ls0, 32); lrun0 += ls0;
    ls1 += __shfl_xor(ls1, 16); ls1 += __shfl_xor(ls1, 32); lrun1 += ls1;

    // ---- O += P @ V : single b128 B-frag (global j-permuted layout)
    __builtin_amdgcn_s_setprio(1);
#pragma unroll
    for (int dc = 0; dc < 16; ++dc) {
      const int d = dc * 16 + qa;
      const short8 vf = *(const short8*)(VsB + d * 64 + ((hi * 16) ^ ((d & 3) << 4)));
      acc[0][dc] = __builtin_amdgcn_mfma_f32_16x16x32_bf16(af0, vf, acc[0][dc], 0, 0, 0);
      acc[1][dc] = __builtin_amdgcn_mfma_f32_16x16x32_bf16(af1, vf, acc[1][dc], 0, 0, 0);
    }
    __builtin_amdgcn_s_setprio(0);
    __syncthreads();
    buf ^= 1;
  }

  // ---- epilogue: acc[t][dc][r] = O[q=t*16+hi*4+r][d=dc*16+qa] (unnormalized)
  if (nsplit == 1) {
    float inv0[4], inv1[4];
#pragma unroll
    for (int r = 0; r < 4; ++r) {
      inv0[r] = 1.f / __shfl(lrun0, hi * 4 + r);
      inv1[r] = 1.f / __shfl(lrun1, hi * 4 + r);
    }
    float* Ob = Out + (size_t)(b * SLEN + q0 + w * 32) * DIMD;
#pragma unroll
    for (int dc = 0; dc < 16; ++dc)
#pragma unroll
      for (int r = 0; r < 4; ++r) {
        Ob[(size_t)(hi * 4 + r) * DIMD + dc * 16 + qa] = acc[0][dc][r] * inv0[r];
        Ob[(size_t)(16 + hi * 4 + r) * DIMD + dc * 16 + qa] = acc[1][dc][r] * inv1[r];
      }
  } else {
    const size_t qrow0 = (size_t)b * SLEN + q0 + w * 32;
#pragma unroll
    for (int dc = 0; dc < 16; ++dc)
#pragma unroll
      for (int r = 0; r < 4; ++r) {
        Op[((qrow0 + hi * 4 + r) * nsplit + split) * DIMD + dc * 16 + qa] = acc[0][dc][r];
        Op[((qrow0 + 16 + hi * 4 + r) * nsplit + split) * DIMD + dc * 16 + qa] = acc[1][dc][r];
      }
    if (hi == 0) {
      size_t i = (qrow0 + qa) * nsplit + split;
      MLp[i * 2] = mold0; MLp[i * 2 + 1] = lrun0;
      i = (qrow0 + 16 + qa) * nsplit + split;
      MLp[i * 2] = mold1; MLp[i * 2 + 1] = lrun1;
    }
  }
}

// ------------- merge partials across kv-splits -------------
__global__ __launch_bounds__(256) void attn_merge(const float* __restrict__ Op,
                                                  const float* __restrict__ MLp,
                                                  float* __restrict__ Out, int nsplit) {
  const int q = blockIdx.x, d = threadIdx.x;
  float M = -1e30f;
  for (int i = 0; i < nsplit; ++i) M = fmaxf(M, MLp[((size_t)q * nsplit + i) * 2]);
  float L = 0.f, o = 0.f;
  for (int i = 0; i < nsplit; ++i) {
    const float wgt = __expf(MLp[((size_t)q * nsplit + i) * 2] - M);
    L += wgt * MLp[((size_t)q * nsplit + i) * 2 + 1];
    o += wgt * Op[((size_t)q * nsplit + i) * DIMD + d];
  }
  Out[(size_t)q * DIMD + d] = o / L;
}

extern "C" void kernel_launch(void* const* d_in, const int* in_sizes, int n_in,
                              void* d_out, int out_size, void* d_ws, size_t ws_size,
                              hipStream_t stream) {
  const float* X = (const float*)d_in[0];
  const float* W = (const float*)d_in[1];
  const float* bias = (const float*)d_in[2];
  char* wsb = (char*)d_ws;
  ushort* qw = (ushort*)wsb;                       // 8 MB
  ushort* kw = qw + (size_t)16384 * 256;           // 8 MB
  ushort* vtw = kw + (size_t)16384 * 256;          // 8 MB (V^T, j-permuted)
  ushort* wt = vtw + (size_t)16384 * 256;          // 384 KB (W^T bf16)
  const size_t head_bytes = (size_t)3 * 16384 * 256 * 2 + 768 * 256 * 2;
  const size_t per_split = (size_t)16384 * 256 * 4 + (size_t)16384 * 8;
  int nsplit = 1;
  if (ws_size >= head_bytes + 4 * per_split)      nsplit = 4;
  else if (ws_size >= head_bytes + 2 * per_split) nsplit = 2;
  float* Op = (float*)(wsb + head_bytes);
  float* MLp = Op + (size_t)16384 * nsplit * 256;

  wt_prep<<<dim3(24), 256, 0, stream>>>(W, wt);
  qkv_proj<<<dim3(128, 3), 256, 0, stream>>>(X, wt, bias, qw, kw, vtw);
  flash_attn<<<dim3(128 * nsplit), 256, 0, stream>>>(qw, kw, vtw, (float*)d_out,
                                                     Op, MLp, nsplit, 4096 / nsplit);
  if (nsplit > 1)
    attn_merge<<<dim3(16384), 256, 0, stream>>>(Op, MLp, (float*)d_out, nsplit);
}